// Round 6
// baseline (853.004 us; speedup 1.0000x reference)
//
#include <hip/hip_runtime.h>

// WaveFDTD2D, persistent cooperative kernel: 1 launch, 32 phases x 16 steps.
// 256 blocks (16x16 tiles, 32x32 interior, 64x64 ext) x 256 threads.
// Wave w owns 16 contiguous ext rows at lane=ez: z-neighbors via DPP,
// x-neighbors in registers, only wave-boundary rows through LDS (2R+2W per
// thread-substep), 4-wave barriers. v2 persistent in registers. Cross-block
// halo exchange via double-buffered global sets + per-block phase counters
// (release wbL2 publish / acquire invL2 poll of 8 neighbors, agent scope).
// Deadlock-free: every block bumps its counter every phase (active or not);
// waits only need neighbors' previous-phase publish. Exact L1 cone skip
// keeps never-reached tiles trivial (their interiors stay the init zeros in
// BOTH buffer sets, which is exactly their true field).

#define NXd 512
#define NZd 512
#define NSTEPSd 512
#define NRECd 128
#define DT2f 1.0e-6f
#define INVf 1.0e-2f
#define TBk 16           // steps per phase
#define TIk 32           // tile interior
#define EXTk 64          // TIk + 2*TBk
#define NTILEk 16        // NXd / TIk
#define NPHASEk 32       // NSTEPSd / TBk
#define ROWSk 16         // ext rows per wave (64 rows / 4 waves)

__device__ __forceinline__ float dpp_shr1(float x) {  // lane i <- lane i-1
    int v = __builtin_amdgcn_update_dpp(0, __builtin_bit_cast(int, x),
                                        0x138, 0xF, 0xF, false);  // WAVE_SHR:1
    return __builtin_bit_cast(float, v);
}
__device__ __forceinline__ float dpp_shl1(float x) {  // lane i <- lane i+1
    int v = __builtin_amdgcn_update_dpp(0, __builtin_bit_cast(int, x),
                                        0x130, 0xF, 0xF, false);  // WAVE_SHL:1
    return __builtin_bit_cast(float, v);
}

__global__ __launch_bounds__(256, 1) void fdtd_persist(
    const float* __restrict__ vel, const float* __restrict__ source,
    const int* __restrict__ src_x, const int* __restrict__ src_z,
    const int* __restrict__ rec_x, const int* __restrict__ rec_z,
    float* __restrict__ Ca, float* __restrict__ Oa,
    float* __restrict__ Cb, float* __restrict__ Ob,
    int* __restrict__ ctrs, float* __restrict__ out)
{
    __shared__ float sb[2][8 * EXTk];          // wave-boundary rows, ping-pong
    __shared__ float recLDS[2][EXTk * EXTk];   // receiver cells only, ping-pong

    const int tid = threadIdx.x;
    const int w = tid >> 6;          // wave 0..3 owns ext rows 16w..16w+15
    const int lane = tid & 63;       // ext z coord
    const int bx = blockIdx.y, bz = blockIdx.x;
    const int gx0 = bx * TIk, gz0 = bz * TIk;
    const int ox = gx0 - TBk, oz = gz0 - TBk;
    const int gz = oz + lane;
    const bool zin = (gz >= 0 && gz < NZd);
    const int sx = *src_x, sz = *src_z;
    const int myb = bx * NTILEk + bz;

    // ---- v^2 * dt^2 / (dx*dz), loaded ONCE, persistent in registers ----
    float rV2i[ROWSk];
    #pragma unroll
    for (int i = 0; i < ROWSk; ++i) {
        int gx = ox + ROWSk * w + i;
        float v2 = 0.f;
        if (zin && gx >= 0 && gx < NXd) {
            float v = vel[gx * NZd + gz];
            v2 = v * v * (DT2f * INVf);   // out-of-domain v2=0 pins zero BC
        }
        rV2i[i] = v2;
    }

    // ---- receiver setup: thread r gathers receiver r; owners write recLDS ----
    bool rOwn = false; int rIdx = 0;
    if (tid < NRECd) {
        int rx = rec_x[tid], rz = rec_z[tid];
        if (rx >= gx0 && rx < gx0 + TIk && rz >= gz0 && rz < gz0 + TIk) {
            rOwn = true;
            rIdx = (rx - ox) * EXTk + (rz - oz);
        }
    }
    bool anyRec = false;           // thread-invariant => block-uniform
    unsigned ownMask = 0;          // which of my 16 rows hold receiver cells
    for (int j = 0; j < NRECd; ++j) {
        int rx = rec_x[j], rz = rec_z[j];
        if (rx >= gx0 && rx < gx0 + TIk && rz >= gz0 && rz < gz0 + TIk) {
            anyRec = true;
            int exr = rx - ox, exc = rz - oz;
            if ((exr >> 4) == w && exc == lane) ownMask |= 1u << (exr & 15);
        }
    }

    // ---- source setup (any block whose EXT region contains the source) ----
    const int exs = sx - ox, ezs = sz - oz;
    const bool srcHere = exs >= 0 && exs < EXTk && ezs >= 0 && ezs < EXTk &&
                         w == (exs >> 4) && lane == ezs;
    const int srcI = exs & 15;

    // ---- init: zero my interior in BOTH buffer sets (ws is 0xAA-poisoned) ----
    if ((w == 1 || w == 2) && lane >= TBk && lane < EXTk - TBk) {
        #pragma unroll
        for (int i = 0; i < ROWSk; ++i) {
            int g = (ox + ROWSk * w + i) * NZd + gz;
            Ca[g] = 0.f; Oa[g] = 0.f; Cb[g] = 0.f; Ob[g] = 0.f;
        }
    }
    __syncthreads();               // drains stores (vmcnt0 before s_barrier)
    if (tid == 0) {
        __threadfence();           // agent release: L2 writeback
        __hip_atomic_store(&ctrs[myb], 1, __ATOMIC_RELEASE,
                           __HIP_MEMORY_SCOPE_AGENT);
    }

    // 8-neighbor table (lanes 0..7 each poll one neighbor)
    int nbIdx = -1;
    if (tid < 8) {
        const int dxs[8] = {-1,-1,-1, 0, 0, 1, 1, 1};
        const int dzs[8] = {-1, 0, 1,-1, 1,-1, 0, 1};
        int nx = bx + dxs[tid], nz = bz + dzs[tid];
        if (nx >= 0 && nx < NTILEk && nz >= 0 && nz < NTILEk)
            nbIdx = nx * NTILEk + nz;
    }

    for (int p = 0; p < NPHASEk; ++p) {
        const int t0 = p * TBk;

        // Exact cone skip: field@t is identically 0 beyond L1 radius t.
        int dxm = max(0, max(ox - sx, sx - (ox + EXTk - 1)));
        int dzm = max(0, max(oz - sz, sz - (oz + EXTk - 1)));
        if (dxm + dzm > t0 + TBk + 1) {
            if (rOwn) {
                #pragma unroll
                for (int s = 0; s < TBk; ++s)
                    out[tid * NSTEPSd + t0 + s] = 0.f;
            }
            __syncthreads();       // block-uniform branch; keep converged
            if (tid == 0)
                __hip_atomic_store(&ctrs[myb], p + 2, __ATOMIC_RELEASE,
                                   __HIP_MEMORY_SCOPE_AGENT);
            continue;
        }

        // Wait: all existing neighbors published state@16p (ctr >= p+1).
        if (nbIdx >= 0) {
            while (__hip_atomic_load(&ctrs[nbIdx], __ATOMIC_ACQUIRE,
                                     __HIP_MEMORY_SCOPE_AGENT) < p + 1)
                __builtin_amdgcn_s_sleep(1);
        }
        __syncthreads();

        const float* Cin = (p & 1) ? Cb : Ca;
        const float* Oin = (p & 1) ? Ob : Oa;
        float* Cout = (p & 1) ? Ca : Cb;
        float* Oout = (p & 1) ? Oa : Ob;

        // Load ext region (cur, old) from the read set.
        float rCur[ROWSk], rOld[ROWSk];
        #pragma unroll
        for (int i = 0; i < ROWSk; ++i) {
            int gx = ox + ROWSk * w + i;
            float c = 0.f, o = 0.f;
            if (zin && gx >= 0 && gx < NXd) {
                int g = gx * NZd + gz;
                c = Cin[g]; o = Oin[g];
            }
            rCur[i] = c; rOld[i] = o;
        }

        float sv[TBk];
        if (srcHere) {
            #pragma unroll
            for (int s = 0; s < TBk; ++s) sv[s] = source[t0 + s] * DT2f;
        }

        // Prefill boundary-row buffer for substep 0.
        sb[0][(2 * w) * EXTk + lane] = rCur[0];
        sb[0][(2 * w + 1) * EXTk + lane] = rCur[ROWSk - 1];
        __syncthreads();

        float rv[TBk];
        #pragma unroll
        for (int s = 0; s < TBk; ++s) {
            const float* cbuf = sb[s & 1];
            float* nbuf = sb[(s & 1) ^ 1];
            // Boundary rows from adjacent waves (trapezoid rim garbage at
            // w edges never reaches interior/receivers -- rounds 3-5 proven).
            float up0 = (w > 0) ? cbuf[(2 * w - 1) * EXTk + lane] : 0.f;
            float dn15 = (w < 3) ? cbuf[(2 * w + 2) * EXTk + lane] : 0.f;
            float prev = up0;
            #pragma unroll
            for (int i = 0; i < ROWSk; ++i) {
                float dnv = (i < ROWSk - 1) ? rCur[i + 1] : dn15;
                float lf = dpp_shr1(rCur[i]);
                float rt = dpp_shl1(rCur[i]);
                float sum = (prev + dnv) + (lf + rt);
                float t4 = __builtin_fmaf(-4.f, rCur[i], sum);
                float pm = __builtin_fmaf(2.f, rCur[i], -rOld[i]);
                float nv = __builtin_fmaf(rV2i[i], t4, pm);
                prev = rCur[i];
                rOld[i] = rCur[i];
                rCur[i] = nv;
            }
            // Source injection: post-stencil, pre-recording.
            if (srcHere) {
                #pragma unroll
                for (int i = 0; i < ROWSk; ++i)
                    if (i == srcI) rCur[i] += sv[s];
            }
            nbuf[(2 * w) * EXTk + lane] = rCur[0];
            nbuf[(2 * w + 1) * EXTk + lane] = rCur[ROWSk - 1];
            if (anyRec && ownMask) {
                #pragma unroll
                for (int i = 0; i < ROWSk; ++i)
                    if (ownMask & (1u << i))
                        recLDS[s & 1][(ROWSk * w + i) * EXTk + lane] = rCur[i];
            }
            __syncthreads();
            // Read between barrier s and s+1; next write to this recLDS
            // buffer is in substep s+2, after barrier s+1 -> race-free.
            if (rOwn) rv[s] = recLDS[s & 1][rIdx];
        }

        if (rOwn) {
            #pragma unroll
            for (int s = 0; s < TBk; ++s)
                out[tid * NSTEPSd + t0 + s] = rv[s];
        }
        // Publish interior state@16(p+1) (cur, old) into the write set.
        if ((w == 1 || w == 2) && lane >= TBk && lane < EXTk - TBk) {
            #pragma unroll
            for (int i = 0; i < ROWSk; ++i) {
                int g = (ox + ROWSk * w + i) * NZd + gz;
                Cout[g] = rCur[i];
                Oout[g] = rOld[i];
            }
        }
        __syncthreads();           // drains stores to L2
        if (tid == 0) {
            __threadfence();       // L2 writeback to coherent point
            __hip_atomic_store(&ctrs[myb], p + 2, __ATOMIC_RELEASE,
                               __HIP_MEMORY_SCOPE_AGENT);
        }
    }
}

extern "C" void kernel_launch(void* const* d_in, const int* in_sizes, int n_in,
                              void* d_out, int out_size, void* d_ws, size_t ws_size,
                              hipStream_t stream) {
    const float* vel    = (const float*)d_in[0];
    const float* source = (const float*)d_in[1];
    const int*   src_x  = (const int*)d_in[2];
    const int*   src_z  = (const int*)d_in[3];
    const int*   rec_x  = (const int*)d_in[4];
    const int*   rec_z  = (const int*)d_in[5];
    float* out = (float*)d_out;

    const size_t F = (size_t)NXd * NZd;
    float* Ca = (float*)d_ws;
    float* Oa = Ca + F;
    float* Cb = Oa + F;
    float* Ob = Cb + F;
    int* ctrs = (int*)(Ob + F);

    // Counters must start at 0 (ws is 0xAA-poisoned; 0xAAAAAAAA would
    // spuriously satisfy every ">= p+1" poll). Fields are zeroed in-kernel.
    hipMemsetAsync(ctrs, 0, NTILEk * NTILEk * sizeof(int), stream);

    void* args[] = {(void*)&vel, (void*)&source, (void*)&src_x, (void*)&src_z,
                    (void*)&rec_x, (void*)&rec_z, (void*)&Ca, (void*)&Oa,
                    (void*)&Cb, (void*)&Ob, (void*)&ctrs, (void*)&out};
    hipLaunchCooperativeKernel((void*)fdtd_persist, dim3(NTILEk, NTILEk),
                               dim3(256), args, 0, stream);
}